// Round 17
// baseline (28.237 us; speedup 1.0000x reference)
//
#include <hip/hip_runtime.h>
#include <math.h>

#define KK 5
#define WPOUT 28
#define PPI 784          // patches per image (28*28)
#define NCH 64
#define NPAIR 12544      // patch pairs (A=2k, B=2k+1 always in same row: 28 even)
#define THREADS 256
#define NNODE 21
#define CPB 4            // channels per block: grid 49 x 16 = 784 blocks (~3/CU)

typedef float f32x32 __attribute__((ext_vector_type(32)));
typedef float f32x16 __attribute__((ext_vector_type(16)));
typedef _Float16 h2  __attribute__((ext_vector_type(2)));

static __device__ __forceinline__ h2 u2h(unsigned u) { return __builtin_bit_cast(h2, u); }
static __device__ __forceinline__ unsigned h2u(h2 h) { return __builtin_bit_cast(unsigned, h); }
static __device__ __forceinline__ unsigned f2u(float f) { return __builtin_bit_cast(unsigned, f); }
static __device__ __forceinline__ float u2f(unsigned u) { return __builtin_bit_cast(float, u); }

// pack two f32 -> packed f16 pair in one dword (v_cvt_pkrtz_f16_f32)
static __device__ __forceinline__ unsigned packpair(float a, float b) {
    const auto pk = __builtin_amdgcn_cvt_pkrtz(a, b);   // __fp16 ext_vector(2)
    return __builtin_bit_cast(unsigned, pk);
}

// r = s * splat(d.half[ODD]) + splat(e.half[ODD])   (packed f16, both output halves)
// VOP3P op_sel[i] = half of src i feeding the LOW result half; op_sel_hi[i] the HIGH.
template <int ODD>
static __device__ __forceinline__ unsigned pkfma_splat(unsigned s, unsigned d, unsigned e) {
    unsigned r;
    if constexpr (ODD)
        asm("v_pk_fma_f16 %0, %1, %2, %3 op_sel:[0,1,1] op_sel_hi:[1,1,1]"
            : "=v"(r) : "v"(s), "v"(d), "v"(e));
    else
        asm("v_pk_fma_f16 %0, %1, %2, %3 op_sel:[0,0,0] op_sel_hi:[1,0,0]"
            : "=v"(r) : "v"(s), "v"(d), "v"(e));
    return r;
}

// One 4-input LUT node for a packed patch pair (both patches in each h2).
// E = e[0..7] (f16, 4 dwords), D = d[0..7]; e = sigmoid(lut[2k]), d = sigmoid(lut[2k+1]) - e.
// s0 = most significant address bit (contracted last), s3 least significant.
static __device__ __forceinline__ unsigned node_pair(uint4 E, uint4 D,
                                                     unsigned s0, unsigned s1,
                                                     unsigned s2, unsigned s3) {
    const unsigned Ea[4] = { E.x, E.y, E.z, E.w };
    const unsigned Da[4] = { D.x, D.y, D.z, D.w };
    unsigned v[8];
#pragma unroll
    for (int k = 0; k < 8; k += 2) {
        v[k]     = pkfma_splat<0>(s3, Da[k >> 1], Ea[k >> 1]);
        v[k + 1] = pkfma_splat<1>(s3, Da[k >> 1], Ea[k >> 1]);
    }
    const h2 s2h = u2h(s2), s1h = u2h(s1), s0h = u2h(s0);
    h2 w[4];
#pragma unroll
    for (int k = 0; k < 4; ++k) {
        const h2 ve = u2h(v[2 * k]), vo = u2h(v[2 * k + 1]);
        w[k] = s2h * (vo - ve) + ve;        // full-register v_pk ops, no splats
    }
    const h2 u0 = s1h * (w[1] - w[0]) + w[0];
    const h2 u1 = s1h * (w[3] - w[2]) + w[2];
    return h2u(s0h * (u1 - u0) + u0);
}

__global__ __launch_bounds__(THREADS)
void dwn_conv_lut_kernel(const float* __restrict__ x,     // [32,1,32,32]
                         const float* __restrict__ lut0,  // [64,16,16]
                         const float* __restrict__ lut1,  // [64,4,16]
                         const float* __restrict__ lut2,  // [64,1,16]
                         const int*   __restrict__ idx0,  // [64,16,4]
                         const int*   __restrict__ idx1,  // [64,4,4]
                         const int*   __restrict__ idx2,  // [64,1,4]
                         float*       __restrict__ out)   // [32,64,28,28]
{
    __shared__ __align__(16) _Float16 lut[CPB][NNODE][16];   // per channel: [0..7]=e, [8..15]=d

    const int tid = threadIdx.x;
    const int c0  = blockIdx.y * CPB;

    // ---- stage sigmoided LUTs (f16 e,d) for CPB channels: 4*21*8 = 672 pairs ----
    for (int t = tid; t < CPB * NNODE * 8; t += THREADS) {
        const int cc   = t / (NNODE * 8);
        const int r    = t - cc * (NNODE * 8);
        const int node = r >> 3, k = r & 7;
        const int c    = c0 + cc;
        const float* src;
        if (node < 16)      src = lut0 + (c * 16 + node) * 16;
        else if (node < 20) src = lut1 + (c * 4 + (node - 16)) * 16;
        else                src = lut2 + c * 16;
        const float a = src[2 * k], b = src[2 * k + 1];
        const float ea = 1.0f / (1.0f + __expf(-a));
        const float eb = 1.0f / (1.0f + __expf(-b));
        lut[cc][node][k]     = (_Float16)ea;
        lut[cc][node][k + 8] = (_Float16)(eb - ea);
    }

    // ---- one packed patch pair per thread (A=2*pi, B=2*pi+1, same row) ----
    const int pi = blockIdx.x * THREADS + tid;   // 49*256 == 12544, no tail
    const int p  = 2 * pi;                       // patch A
    const int b  = p / PPI;
    const int q  = p - b * PPI;                  // even
    const int i  = q / WPOUT;
    const int j  = q - i * WPOUT;                // even -> 8B aligned; j<=26 so pair in-row

    const float* rp0 = x + b * 1024 + i * 32 + j;
    f32x32 pv;                                   // movrel vector; contents = h2 pairs; CHANNEL-INDEPENDENT
#pragma unroll
    for (int di = 0; di < KK; ++di) {
        const float2* r2 = (const float2*)(rp0 + di * 32);
        const float2 w01 = r2[0], w23 = r2[1], w45 = r2[2];
        const float w[6] = { w01.x, w01.y, w23.x, w23.y, w45.x, w45.y };
#pragma unroll
        for (int dj = 0; dj < KK; ++dj) {
            pv[di * 5 + dj] = u2f(packpair(w[dj], w[dj + 1]));
        }
    }

    __syncthreads();   // LUTs ready

    float* outp = out + b * (NCH * PPI) + q;     // + c*PPI per channel

    // ---- channel loop: pv reused, LUTs from LDS, full node pipeline per channel ----
    for (int cc = 0; cc < CPB; ++cc) {
        const int c = c0 + cc;

        // layer 0: 16 nodes; uniform-index movrel gathers
        const int* id0 = idx0 + c * 64;          // block-uniform -> scalar loads
        f32x16 h0;
#pragma unroll
        for (int m = 0; m < 16; ++m) {
            const uint4* row = (const uint4*)&lut[cc][m][0];
            const uint4 E = row[0], D = row[1];  // 2x ds_read_b128
            const int i0 = __builtin_amdgcn_readfirstlane(id0[m * 4 + 0]);
            const int i1 = __builtin_amdgcn_readfirstlane(id0[m * 4 + 1]);
            const int i2 = __builtin_amdgcn_readfirstlane(id0[m * 4 + 2]);
            const int i3 = __builtin_amdgcn_readfirstlane(id0[m * 4 + 3]);
            h0[m] = u2f(node_pair(E, D, f2u(pv[i0]), f2u(pv[i1]), f2u(pv[i2]), f2u(pv[i3])));
        }

        // layer 1: 4 nodes; movrel gathers from h0
        const int* id1 = idx1 + c * 16;
        unsigned h1[4];                           // static-indexed only
#pragma unroll
        for (int m = 0; m < 4; ++m) {
            const uint4* row = (const uint4*)&lut[cc][16 + m][0];
            const uint4 E = row[0], D = row[1];
            const int i0 = __builtin_amdgcn_readfirstlane(id1[m * 4 + 0]);
            const int i1 = __builtin_amdgcn_readfirstlane(id1[m * 4 + 1]);
            const int i2 = __builtin_amdgcn_readfirstlane(id1[m * 4 + 2]);
            const int i3 = __builtin_amdgcn_readfirstlane(id1[m * 4 + 3]);
            h1[m] = node_pair(E, D, f2u(h0[i0]), f2u(h0[i1]), f2u(h0[i2]), f2u(h0[i3]));
        }

        // layer 2: 1 node; 4-way uniform select (constant after unroll)
        const int* id2 = idx2 + c * 4;
        unsigned s[4];
#pragma unroll
        for (int jj = 0; jj < 4; ++jj) {
            const int ii = __builtin_amdgcn_readfirstlane(id2[jj]);
            s[jj] = (ii == 0) ? h1[0] : (ii == 1) ? h1[1] : (ii == 2) ? h1[2] : h1[3];
        }
        const uint4* row2 = (const uint4*)&lut[cc][20][0];
        const h2 r = u2h(node_pair(row2[0], row2[1], s[0], s[1], s[2], s[3]));

        // store: two consecutive q (q even) -> aligned float2
        float2* o = (float2*)(outp + c * PPI);
        *o = make_float2((float)r[0], (float)r[1]);
    }
}

extern "C" void kernel_launch(void* const* d_in, const int* in_sizes, int n_in,
                              void* d_out, int out_size, void* d_ws, size_t ws_size,
                              hipStream_t stream) {
    const float* x    = (const float*)d_in[0];
    const float* lut0 = (const float*)d_in[1];
    const float* lut1 = (const float*)d_in[2];
    const float* lut2 = (const float*)d_in[3];
    const int*   idx0 = (const int*)d_in[4];
    const int*   idx1 = (const int*)d_in[5];
    const int*   idx2 = (const int*)d_in[6];
    float* out = (float*)d_out;

    dim3 grid(NPAIR / THREADS, NCH / CPB);   // 49 x 16 = 784 blocks
    dim3 block(THREADS);
    dwn_conv_lut_kernel<<<grid, block, 0, stream>>>(x, lut0, lut1, lut2,
                                                    idx0, idx1, idx2, out);
}

// Round 18
// 22.127 us; speedup vs baseline: 1.2761x; 1.2761x over previous
//
#include <hip/hip_runtime.h>
#include <math.h>

#define KK 5
#define WPOUT 28
#define PPI 784          // patches per image (28*28)
#define NCH 64
#define NPAIR 12544      // patch pairs (A=2k, B=2k+1 always in same row: 28 even)
#define THREADS 256
#define NNODE 21

typedef float f32x32 __attribute__((ext_vector_type(32)));
typedef float f32x16 __attribute__((ext_vector_type(16)));
typedef _Float16 h2  __attribute__((ext_vector_type(2)));

static __device__ __forceinline__ h2 u2h(unsigned u) { return __builtin_bit_cast(h2, u); }
static __device__ __forceinline__ unsigned h2u(h2 h) { return __builtin_bit_cast(unsigned, h); }
static __device__ __forceinline__ unsigned f2u(float f) { return __builtin_bit_cast(unsigned, f); }
static __device__ __forceinline__ float u2f(unsigned u) { return __builtin_bit_cast(float, u); }

// pack two f32 -> packed f16 pair in one dword (v_cvt_pkrtz_f16_f32)
static __device__ __forceinline__ unsigned packpair(float a, float b) {
    const auto pk = __builtin_amdgcn_cvt_pkrtz(a, b);   // __fp16 ext_vector(2)
    return __builtin_bit_cast(unsigned, pk);
}

// r = s * splat(d.half[ODD]) + splat(e.half[ODD])   (packed f16, both output halves)
// VOP3P op_sel[i] = half of src i feeding the LOW result half; op_sel_hi[i] the HIGH.
template <int ODD>
static __device__ __forceinline__ unsigned pkfma_splat(unsigned s, unsigned d, unsigned e) {
    unsigned r;
    if constexpr (ODD)
        asm("v_pk_fma_f16 %0, %1, %2, %3 op_sel:[0,1,1] op_sel_hi:[1,1,1]"
            : "=v"(r) : "v"(s), "v"(d), "v"(e));
    else
        asm("v_pk_fma_f16 %0, %1, %2, %3 op_sel:[0,0,0] op_sel_hi:[1,0,0]"
            : "=v"(r) : "v"(s), "v"(d), "v"(e));
    return r;
}

// One 4-input LUT node for a packed patch pair (both patches in each h2).
// E = e[0..7] (f16, 4 dwords), D = d[0..7]; e = sigmoid(lut[2k]), d = sigmoid(lut[2k+1]) - e.
// s0 = most significant address bit (contracted last), s3 least significant.
static __device__ __forceinline__ unsigned node_pair(uint4 E, uint4 D,
                                                     unsigned s0, unsigned s1,
                                                     unsigned s2, unsigned s3) {
    const unsigned Ea[4] = { E.x, E.y, E.z, E.w };
    const unsigned Da[4] = { D.x, D.y, D.z, D.w };
    unsigned v[8];
#pragma unroll
    for (int k = 0; k < 8; k += 2) {
        v[k]     = pkfma_splat<0>(s3, Da[k >> 1], Ea[k >> 1]);
        v[k + 1] = pkfma_splat<1>(s3, Da[k >> 1], Ea[k >> 1]);
    }
    const h2 s2h = u2h(s2), s1h = u2h(s1), s0h = u2h(s0);
    h2 w[4];
#pragma unroll
    for (int k = 0; k < 4; ++k) {
        const h2 ve = u2h(v[2 * k]), vo = u2h(v[2 * k + 1]);
        w[k] = s2h * (vo - ve) + ve;        // full-register v_pk ops, no splats
    }
    const h2 u0 = s1h * (w[1] - w[0]) + w[0];
    const h2 u1 = s1h * (w[3] - w[2]) + w[2];
    return h2u(s0h * (u1 - u0) + u0);
}

__global__ __launch_bounds__(THREADS, 4)   // 128-VGPR budget: room for the depth-2 prefetch pipeline
void dwn_conv_lut_kernel(const float* __restrict__ x,     // [32,1,32,32]
                         const float* __restrict__ lut0,  // [64,16,16]
                         const float* __restrict__ lut1,  // [64,4,16]
                         const float* __restrict__ lut2,  // [64,1,16]
                         const int*   __restrict__ idx0,  // [64,16,4]
                         const int*   __restrict__ idx1,  // [64,4,4]
                         const int*   __restrict__ idx2,  // [64,1,4]
                         float*       __restrict__ out)   // [32,64,28,28]
{
    __shared__ __align__(16) _Float16 lut[NNODE][16];   // [0..7]=e, [8..15]=d (f16), 32B/row

    const int tid = threadIdx.x;
    const int c   = blockIdx.y;

    // ---- stage sigmoided LUTs as f16 (e,d): 21 nodes * 8 pairs = 168 ----
    if (tid < NNODE * 8) {
        const int k = tid & 7, node = tid >> 3;
        const float* src;
        if (node < 16)      src = lut0 + (c * 16 + node) * 16;
        else if (node < 20) src = lut1 + (c * 4 + (node - 16)) * 16;
        else                src = lut2 + c * 16;
        const float a = src[2 * k], b = src[2 * k + 1];
        const float ea = 1.0f / (1.0f + __expf(-a));
        const float eb = 1.0f / (1.0f + __expf(-b));
        lut[node][k]     = (_Float16)ea;
        lut[node][k + 8] = (_Float16)(eb - ea);
    }

    // ---- one packed patch pair per thread (A=2*pi, B=2*pi+1, same row) ----
    const int pi = blockIdx.x * THREADS + tid;   // 49*256 == 12544, no tail
    const int p  = 2 * pi;                       // patch A
    const int b  = p / PPI;
    const int q  = p - b * PPI;                  // even
    const int i  = q / WPOUT;
    const int j  = q - i * WPOUT;                // even -> 8B aligned; j<=26 so pair in-row

    const float* rp0 = x + b * 1024 + i * 32 + j;
    f32x32 pv;                                   // f32-typed movrel vector; contents = h2 pairs
#pragma unroll
    for (int di = 0; di < KK; ++di) {
        const float2* r2 = (const float2*)(rp0 + di * 32);
        const float2 w01 = r2[0], w23 = r2[1], w45 = r2[2];
        const float w[6] = { w01.x, w01.y, w23.x, w23.y, w45.x, w45.y };
#pragma unroll
        for (int dj = 0; dj < KK; ++dj) {
            pv[di * 5 + dj] = u2f(packpair(w[dj], w[dj + 1]));
        }
    }

    __syncthreads();   // LUTs ready

    // ---- layer 0: 16 nodes; DEPTH-2 software pipeline on (E, D, idx quad) ----
    const uint4* rows = (const uint4*)&lut[0][0];        // 2 x uint4 per node
    const uint4* idq  = (const uint4*)(idx0 + c * 64);   // 1 x uint4 per node, 16B-aligned

    uint4 Ea = rows[0], Da = rows[1], Ia = idq[0];       // node m
    uint4 Eb = rows[2], Db = rows[3], Ib = idq[1];       // node m+1

    f32x16 h0;
#pragma unroll
    for (int m = 0; m < 16; ++m) {
        uint4 Ec, Dc, Ic;                                 // prefetch node m+2
        if (m < 14) { Ec = rows[2 * m + 4]; Dc = rows[2 * m + 5]; Ic = idq[m + 2]; }

        const int i0 = __builtin_amdgcn_readfirstlane((int)Ia.x);
        const int i1 = __builtin_amdgcn_readfirstlane((int)Ia.y);
        const int i2 = __builtin_amdgcn_readfirstlane((int)Ia.z);
        const int i3 = __builtin_amdgcn_readfirstlane((int)Ia.w);
        h0[m] = u2f(node_pair(Ea, Da, f2u(pv[i0]), f2u(pv[i1]), f2u(pv[i2]), f2u(pv[i3])));

        Ea = Eb; Da = Db; Ia = Ib;                        // rotate pipeline (static, unrolled)
        if (m < 14) { Eb = Ec; Db = Dc; Ib = Ic; }
    }

    // ---- layer 1: 4 nodes; movrel gathers from h0 ----
    const int* id1 = idx1 + c * 16;
    unsigned h1[4];                   // static-indexed only
#pragma unroll
    for (int m = 0; m < 4; ++m) {
        const uint4* row = (const uint4*)&lut[16 + m][0];
        const uint4 E = row[0], D = row[1];
        const int i0 = __builtin_amdgcn_readfirstlane(id1[m * 4 + 0]);
        const int i1 = __builtin_amdgcn_readfirstlane(id1[m * 4 + 1]);
        const int i2 = __builtin_amdgcn_readfirstlane(id1[m * 4 + 2]);
        const int i3 = __builtin_amdgcn_readfirstlane(id1[m * 4 + 3]);
        h1[m] = node_pair(E, D, f2u(h0[i0]), f2u(h0[i1]), f2u(h0[i2]), f2u(h0[i3]));
    }

    // ---- layer 2: 1 node; 4-way uniform select (constant after unroll) ----
    const int* id2 = idx2 + c * 4;
    unsigned s[4];
#pragma unroll
    for (int jj = 0; jj < 4; ++jj) {
        const int ii = __builtin_amdgcn_readfirstlane(id2[jj]);
        s[jj] = (ii == 0) ? h1[0] : (ii == 1) ? h1[1] : (ii == 2) ? h1[2] : h1[3];
    }
    const uint4* row2 = (const uint4*)&lut[20][0];
    const h2 r = u2h(node_pair(row2[0], row2[1], s[0], s[1], s[2], s[3]));

    // ---- store: two consecutive q (q even) -> aligned float2 ----
    float2* o = (float2*)(out + (b * NCH + c) * PPI + q);
    *o = make_float2((float)r[0], (float)r[1]);
}

extern "C" void kernel_launch(void* const* d_in, const int* in_sizes, int n_in,
                              void* d_out, int out_size, void* d_ws, size_t ws_size,
                              hipStream_t stream) {
    const float* x    = (const float*)d_in[0];
    const float* lut0 = (const float*)d_in[1];
    const float* lut1 = (const float*)d_in[2];
    const float* lut2 = (const float*)d_in[3];
    const int*   idx0 = (const int*)d_in[4];
    const int*   idx1 = (const int*)d_in[5];
    const int*   idx2 = (const int*)d_in[6];
    float* out = (float*)d_out;

    dim3 grid(NPAIR / THREADS, NCH);   // 49 x 64
    dim3 block(THREADS);
    dwn_conv_lut_kernel<<<grid, block, 0, stream>>>(x, lut0, lut1, lut2,
                                                    idx0, idx1, idx2, out);
}